// Round 19
// baseline (5350.602 us; speedup 1.0000x reference)
//
#include <hip/hip_runtime.h>
#include <math.h>

#define NB 1024
#define NS 76
#define SSA 34
#define SSB 28
#define SSP 14
#define DM 512
#define NH 8
#define DH 64
#define NE 16
#define CAP 19
#define NSLOT (NB*CAP)
#define KSPLIT 8
#define NELM ((size_t)NB*NS*DM)

typedef unsigned short ushortt;
typedef short s16x4 __attribute__((ext_vector_type(4)));
typedef short s16x8 __attribute__((ext_vector_type(8)));
typedef float f32x4 __attribute__((ext_vector_type(4)));
typedef unsigned int u32x4 __attribute__((ext_vector_type(4)));

__device__ __forceinline__ ushortt f2bf(float f) {
  union { float f; unsigned int u; } v; v.f = f;
  unsigned int u = v.u;
  u += 0x7fffu + ((u >> 16) & 1u);
  return (ushortt)(u >> 16);
}
__device__ __forceinline__ float bf2f(ushortt s) {
  union { unsigned int u; float f; } v; v.u = ((unsigned int)s) << 16;
  return v.f;
}
__device__ __forceinline__ void split2(float v, ushortt& h, ushortt& l) {
  h = f2bf(v);
  l = f2bf(v - bf2f(h));
}
__device__ __forceinline__ unsigned int split_pk(float v) {
  ushortt h, l; split2(v, h, l);
  return ((unsigned int)l << 16) | (unsigned int)h;
}
__device__ __forceinline__ float gelu_tanh(float x) {
  float x3 = x*x*x;
  return 0.5f*x*(1.0f + tanhf(0.7978845608028654f*(x + 0.044715f*x3)));
}

// ---------------- embedding + sinusoidal PE -> X f32 + Xh/Xl planes ----------------
__global__ __launch_bounds__(256) void k_embed(
    const int* __restrict__ ta, const int* __restrict__ tb, const int* __restrict__ tp,
    const float* __restrict__ Wa, const float* __restrict__ Wb, const float* __restrict__ Wp,
    float* __restrict__ X, ushortt* __restrict__ Xh, ushortt* __restrict__ Xl) {
  int idx = blockIdx.x * 256 + threadIdx.x;
  if (idx >= NB*NS*DM) return;
  int d = idx & (DM-1);
  int bs = idx >> 9;
  int s = bs % NS, b = bs / NS;
  int sl, tok; const float* W;
  if (s < SSA)          { sl = s;         tok = ta[b*SSA+sl]; W = Wa; }
  else if (s < SSA+SSB) { sl = s-SSA;     tok = tb[b*SSB+sl]; W = Wb; }
  else                  { sl = s-SSA-SSB; tok = tp[b*SSP+sl]; W = Wp; }
  float dv = expf((float)(d & ~1) * (-9.210340371976184f/512.0f));
  float ang = (float)sl * dv;
  float pe = (d & 1) ? cosf(ang) : sinf(ang);
  float v = W[(size_t)tok*DM + d] + pe;
  X[idx] = v;
  ushortt h, l; split2(v, h, l);
  Xh[idx] = h; Xl[idx] = l;
}

// ---------------- f32 -> hi/lo plane split (same layout) ----------------
__global__ __launch_bounds__(256) void k_split_planes(
    const float* __restrict__ in, ushortt* __restrict__ hp, ushortt* __restrict__ lp, int n) {
  int i = blockIdx.x * 256 + threadIdx.x;
  if (i < n) { ushortt h, l; split2(in[i], h, l); hp[i] = h; lp[i] = l; }
}

// ---------------- weight relayout: f32 [mat][K][N] -> k-major hi/lo planes [mat][N][K] ----------------
__global__ __launch_bounds__(256) void k_relayout(
    const float* __restrict__ in, ushortt* __restrict__ oh, ushortt* __restrict__ ol,
    int K, int N) {
  __shared__ float tile[64][65];
  long long base = (long long)blockIdx.z * K * N;
  int k0 = blockIdx.x * 64, n0 = blockIdx.y * 64;
  int t = threadIdx.x;
  int tx = t & 63, ty = t >> 6;
#pragma unroll
  for (int i = 0; i < 64; i += 4) {
    int k = k0 + ty + i, n = n0 + tx;
    if (n < N) tile[ty + i][tx] = in[base + (long long)k*N + n];
  }
  __syncthreads();
#pragma unroll
  for (int i = 0; i < 64; i += 4) {
    int n = n0 + ty + i, k = k0 + tx;
    if (n < N) {
      ushortt h, l; split2(tile[tx][ty + i], h, l);
      long long o = base + (long long)n*K + k;
      oh[o] = h; ol[o] = l;
    }
  }
}

// ---------------- split-plane MFMA GEMM, 128x128 tile, BK=32, 3 MFMA/frag ----------------
template<int AHEAD, int CM, int MW>
__global__ __launch_bounds__(256, MW) void k_mfma(
    const ushortt* __restrict__ Ahg, const ushortt* __restrict__ Alg,
    const ushortt* __restrict__ Bhg, const ushortt* __restrict__ Blg,
    float* __restrict__ Cp,
    int N, int K, int lda, int KB, int ldc,
    int rpg, int pitch, int roff, int seg, int cb0,
    long long bstride, int bshift, long long qst, long long csplit) {
  __shared__ short Ah[128][36], Al[128][36], Bh[128][36], Bl[128][36];
  int t = threadIdx.x;
  int m0 = blockIdx.x * 128, n0 = blockIdx.y * 128;
  int kz = blockIdx.z;
  long long koff = (long long)kz * K;
  int w = t >> 6, lane = t & 63;
  int wm = w >> 1, wn = w & 1;
  int arow = t >> 1, ahalf = t & 1;
  int am = m0 + arow;
  int abi = am / rpg, asl = am - abi*rpg;
  size_t afl = 0;
  if (AHEAD == 0) afl = ((size_t)(abi + cb0)*pitch + roff + asl)*lda + (size_t)koff;
  int bn = t & 127, bkh = t >> 7;
  int gn = n0 + bn;
  const ushortt* Bh_c = nullptr; const ushortt* Bl_c = nullptr;
  if (gn < N) {
    int j = gn >> bshift, col = gn - (j << bshift);
    long long bb = (long long)j*bstride + (long long)col*KB + koff;
    Bh_c = Bhg + bb; Bl_c = Blg + bb;
  }
  f32x4 acc[4][4];
#pragma unroll
  for (int i = 0; i < 4; i++)
#pragma unroll
    for (int j = 0; j < 4; j++) acc[i][j] = (f32x4){0.f,0.f,0.f,0.f};

  for (int k0 = 0; k0 < K; k0 += 32) {
    // ---- stage A: contiguous plane copies ----
    {
      size_t ab;
      if (AHEAD == 0) ab = afl + k0 + ahalf*16;
      else {
        int c = k0 + ahalf*16;
        ab = (size_t)(abi*8 + (c >> 6))*((size_t)seg*128) + (size_t)asl*64 + (c & 63);
      }
      s16x8 h0 = *(const s16x8*)&Ahg[ab];
      s16x8 h1 = *(const s16x8*)&Ahg[ab + 8];
      s16x8 l0 = *(const s16x8*)&Alg[ab];
      s16x8 l1 = *(const s16x8*)&Alg[ab + 8];
      *(s16x8*)&Ah[arow][ahalf*16]     = h0;
      *(s16x8*)&Ah[arow][ahalf*16 + 8] = h1;
      *(s16x8*)&Al[arow][ahalf*16]     = l0;
      *(s16x8*)&Al[arow][ahalf*16 + 8] = l1;
    }
    // ---- stage B: contiguous plane copies (k-major) ----
    {
      s16x8 h0 = (s16x8)(short)0, h1v = (s16x8)(short)0;
      s16x8 l0 = (s16x8)(short)0, l1v = (s16x8)(short)0;
      if (Bh_c) {
        h0  = *(const s16x8*)&Bh_c[k0 + bkh*16];
        h1v = *(const s16x8*)&Bh_c[k0 + bkh*16 + 8];
        l0  = *(const s16x8*)&Bl_c[k0 + bkh*16];
        l1v = *(const s16x8*)&Bl_c[k0 + bkh*16 + 8];
      }
      *(s16x8*)&Bh[bn][bkh*16]     = h0;
      *(s16x8*)&Bh[bn][bkh*16 + 8] = h1v;
      *(s16x8*)&Bl[bn][bkh*16]     = l0;
      *(s16x8*)&Bl[bn][bkh*16 + 8] = l1v;
    }
    __syncthreads();
    s16x8 ahf[4], alf[4];
#pragma unroll
    for (int fm = 0; fm < 4; fm++) {
      int r = wm*64 + fm*16 + (lane & 15);
      int cofs = (lane >> 4)*8;
      ahf[fm] = *(const s16x8*)&Ah[r][cofs];
      alf[fm] = *(const s16x8*)&Al[r][cofs];
    }
#pragma unroll
    for (int fn = 0; fn < 4; fn++) {
      int r = wn*64 + fn*16 + (lane & 15);
      int cofs = (lane >> 4)*8;
      s16x8 bhf = *(const s16x8*)&Bh[r][cofs];
      s16x8 blf = *(const s16x8*)&Bl[r][cofs];
#pragma unroll
      for (int fm = 0; fm < 4; fm++) {
        acc[fm][fn] = __builtin_amdgcn_mfma_f32_16x16x32_bf16(ahf[fm], bhf, acc[fm][fn], 0, 0, 0);
        acc[fm][fn] = __builtin_amdgcn_mfma_f32_16x16x32_bf16(alf[fm], bhf, acc[fm][fn], 0, 0, 0);
        acc[fm][fn] = __builtin_amdgcn_mfma_f32_16x16x32_bf16(ahf[fm], blf, acc[fm][fn], 0, 0, 0);
      }
    }
    __syncthreads();
  }
  // ---- epilogue ----
#pragma unroll
  for (int fm = 0; fm < 4; fm++) {
#pragma unroll
    for (int jj = 0; jj < 4; jj++) {
      int mrow = m0 + wm*64 + fm*16 + (lane >> 4)*4 + jj;
      int bi = mrow / rpg, sl = mrow - bi*rpg;
#pragma unroll
      for (int fn = 0; fn < 4; fn++) {
        int ncol = n0 + wn*64 + fn*16 + (lane & 15);
        float vv = acc[fm][fn][jj];
        if (CM == 0) {
          if (ncol < N) Cp[(long long)kz*csplit + (size_t)(bi*pitch + roff + sl)*ldc + ncol] = vv;
        } else {
          int j = ncol >> 9, rem = ncol & 511;
          int hh = rem >> 6, dd = rem & 63;
          Cp[(long long)j*qst + ((size_t)(bi*8 + hh)*seg + sl)*64 + dd] = vv;
        }
      }
    }
  }
}

// ---------------- k-split reduce ----------------
__global__ __launch_bounds__(256) void k_ksum(
    const float* __restrict__ P, float* __restrict__ h1) {
  int i = blockIdx.x * 256 + threadIdx.x;
  if (i >= NB*1000) return;
  float s = 0.f;
#pragma unroll
  for (int z = 0; z < KSPLIT; z++) s += P[(size_t)z*NB*1000 + i];
  h1[i] = s;
}

// ---------------- attention core per (b,h): f32 QKV in, hi/lo planes over own Q slice ----------------
__global__ __launch_bounds__(256) void k_attn2(
    float* __restrict__ Qb, const float* __restrict__ Kb, const float* __restrict__ Vb, int seg) {
  __shared__ float Qs[NS][65], Ks[NS][65], Vs[NS][65];
  __shared__ float pb[4][128];
  int b = blockIdx.x, h = blockIdx.y;
  size_t base = ((size_t)(b*8 + h)) * seg * 64;
  int t = threadIdx.x, w = t >> 6, lane = t & 63;
  for (int i = t; i < seg*64; i += 256) {
    int r = i >> 6, d = i & 63;
    Qs[r][d] = Qb[base + i];
    Ks[r][d] = Kb[base + i];
    Vs[r][d] = Vb[base + i];
  }
  __syncthreads();
  ushortt* Ou = (ushortt*)Qb;      // write planes into own (dead) Q slice
  size_t ub2 = 2*base;
  for (int qi = w; qi < seg; qi += 4) {
    float s1 = -1e30f, s2 = -1e30f;
    int j1 = lane, j2 = lane + 64;
    if (j1 < seg) {
      float acc = 0.f;
#pragma unroll
      for (int d = 0; d < DH; d++) acc += Qs[qi][d]*Ks[j1][d];
      s1 = acc * 0.125f;
    }
    if (j2 < seg) {
      float acc = 0.f;
#pragma unroll
      for (int d = 0; d < DH; d++) acc += Qs[qi][d]*Ks[j2][d];
      s2 = acc * 0.125f;
    }
    float m = fmaxf(s1, s2);
#pragma unroll
    for (int o = 32; o; o >>= 1) m = fmaxf(m, __shfl_xor(m, o));
    float p1 = (j1 < seg) ? expf(s1 - m) : 0.f;
    float p2 = (j2 < seg) ? expf(s2 - m) : 0.f;
    float l = p1 + p2;
#pragma unroll
    for (int o = 32; o; o >>= 1) l += __shfl_xor(l, o);
    float inv = 1.f / l;
    pb[w][lane] = p1 * inv;
    pb[w][lane + 64] = p2 * inv;
    float o = 0.f;
    for (int j = 0; j < seg; j++) o += pb[w][j] * Vs[j][lane];
    ushortt hh, ll; split2(o, hh, ll);
    Ou[ub2 + (size_t)qi*64 + lane] = hh;
    Ou[ub2 + (size_t)seg*64 + (size_t)qi*64 + lane] = ll;
  }
}

// ---------------- residual add + RMSNorm: X f32 exact, planes emitted ----------------
__global__ __launch_bounds__(256) void k_addnorm(
    float* __restrict__ X, ushortt* __restrict__ Xh, ushortt* __restrict__ Xl,
    const float* __restrict__ U, const float* __restrict__ w,
    int seg, int boff, int cb0) {
  int r = blockIdx.x, t = threadIdx.x;
  int b = r / seg + cb0, s = r - (r / seg)*seg;
  size_t xb = ((size_t)b*NS + boff + s)*DM;
  size_t ub = (size_t)r*DM;
  float v0 = X[xb+t] + U[ub+t];
  float v1 = X[xb+t+256] + U[ub+t+256];
  float ss = v0*v0 + v1*v1;
#pragma unroll
  for (int o = 32; o; o >>= 1) ss += __shfl_xor(ss, o);
  __shared__ float red[4];
  if ((t & 63) == 0) red[t>>6] = ss;
  __syncthreads();
  float tot = red[0]+red[1]+red[2]+red[3];
  float sc = rsqrtf(tot * (1.f/512.f) + 1e-6f);
  float o0 = v0*sc*w[t], o1 = v1*sc*w[t+256];
  X[xb+t] = o0; X[xb+t+256] = o1;
  ushortt h, l;
  split2(o0, h, l); Xh[xb+t] = h; Xl[xb+t] = l;
  split2(o1, h, l); Xh[xb+t+256] = h; Xl[xb+t+256] = l;
}

// ---------------- MoE routing: gl matmul + parallel scatter ----------------
__global__ __launch_bounds__(256) void k_route(
    const float* __restrict__ X, const float* __restrict__ Wg,
    int* __restrict__ rec_src, float* __restrict__ rec_gain, int* __restrict__ cnt) {
  __shared__ float gl[NS][NE];
  __shared__ float WgT[NE][DM + 1];
  __shared__ float4 Xs[NS][16];
  __shared__ float g1s[NS], g2s[NS];
  __shared__ int i1s[NS], i2s[NS];
  int b = blockIdx.x, t = threadIdx.x;
  for (int i = t; i < DM*NE; i += 256) {
    int k = i >> 4, e = i & 15;
    WgT[e][k] = Wg[i];
  }
  int e = t & 15;
  int srow = t >> 4;
  float a0[5], a1[5], a2[5], a3[5];
#pragma unroll
  for (int j = 0; j < 5; j++) { a0[j]=0.f; a1[j]=0.f; a2[j]=0.f; a3[j]=0.f; }
  __syncthreads();
  for (int ch = 0; ch < 8; ch++) {
    for (int i = t; i < NS*16; i += 256) {
      int s = i >> 4, f = i & 15;
      Xs[s][f] = *(const float4*)&X[((size_t)b*NS + s)*DM + ch*64 + f*4];
    }
    __syncthreads();
#pragma unroll
    for (int j = 0; j < 5; j++) {
      int s = srow + j*16;
      if (s < NS) {
        const float* wr = &WgT[e][ch*64];
        const float4* xr = &Xs[s][0];
#pragma unroll
        for (int k = 0; k < 64; k += 8) {
          float4 xa = xr[k >> 2];
          float4 xb = xr[(k >> 2) + 1];
          a0[j] += xa.x*wr[k]   + xb.x*wr[k+4];
          a1[j] += xa.y*wr[k+1] + xb.y*wr[k+5];
          a2[j] += xa.z*wr[k+2] + xb.z*wr[k+6];
          a3[j] += xa.w*wr[k+3] + xb.w*wr[k+7];
        }
      }
    }
    __syncthreads();
  }
#pragma unroll
  for (int j = 0; j < 5; j++) {
    int s = srow + j*16;
    if (s < NS) gl[s][e] = (a0[j] + a1[j]) + (a2[j] + a3[j]);
  }
  __syncthreads();
  if (t < NS) {
    float mx = -1e30f;
#pragma unroll
    for (int ee = 0; ee < NE; ee++) mx = fmaxf(mx, gl[t][ee]);
    float sum = 0.f;
#pragma unroll
    for (int ee = 0; ee < NE; ee++) sum += expf(gl[t][ee]-mx);
    int i1 = 0; float l1 = gl[t][0];
#pragma unroll
    for (int ee = 1; ee < NE; ee++) if (gl[t][ee] > l1) { l1 = gl[t][ee]; i1 = ee; }
    int i2 = -1; float l2 = -1e30f;
#pragma unroll
    for (int ee = 0; ee < NE; ee++) if (ee != i1 && gl[t][ee] > l2) { l2 = gl[t][ee]; i2 = ee; }
    float g1 = expf(l1-mx)/sum, g2 = expf(l2-mx)/sum;
    float den = g1 + g2 + 1e-9f;
    g1s[t] = g1/den; g2s[t] = g2/den;
    i1s[t] = i1; i2s[t] = i2;
  }
  __syncthreads();
  // parallel scatter: one thread per (expert, rank) list, ONE atomic each
  if (t < 32) {
    int ee = t >> 1, rank = t & 1;
    int n1 = 0;
    for (int s = 0; s < NS; s++) if (i1s[s] == ee) n1++;
    if (rank == 0) {
      int nloc = n1 < CAP ? n1 : CAP;
      if (nloc > 0) {
        int basei = atomicAdd(&cnt[ee*2+0], nloc);
        size_t lb = (size_t)(ee*2+0)*NSLOT + basei;
        int p = 0;
        for (int s = 0; s < NS && p < nloc; s++) {
          if (i1s[s] == ee) {
            rec_src[lb + p] = b*NS + s;
            rec_gain[lb + p] = g1s[s];
            p++;
          }
        }
      }
    } else {
      int c1 = n1 < CAP ? n1 : CAP;
      int lim = CAP - c1; if (lim < 0) lim = 0;
      int n2 = 0;
      for (int s = 0; s < NS; s++) if (i2s[s] == ee) n2++;
      int nloc = n2 < lim ? n2 : lim;
      if (nloc > 0) {
        int basei = atomicAdd(&cnt[ee*2+1], nloc);
        size_t lb = (size_t)(ee*2+1)*NSLOT + basei;
        int p = 0;
        for (int s = 0; s < NS && p < nloc; s++) {
          if (i2s[s] == ee) {
            rec_src[lb + p] = b*NS + s;
            rec_gain[lb + p] = g2s[s];
            p++;
          }
        }
      }
    }
  }
}

// ---------------- fused expert MLP, 32-row tiles; both ranks in one launch (z=rank), atomic scatter ----------------
__global__ __launch_bounds__(256, 2) void k_expert_mfma(
    const ushortt* __restrict__ Xh, const ushortt* __restrict__ Xl,
    const ushortt* __restrict__ W1h, const ushortt* __restrict__ W1l,
    const ushortt* __restrict__ W2h, const ushortt* __restrict__ W2l,
    float* __restrict__ Y,
    const int* __restrict__ rec_src, const float* __restrict__ rec_gain,
    const int* __restrict__ cnt) {
  __shared__ unsigned int hid[32][517];          // 66176 B (517: stride 5 mod 32 -> conflict-free col reads)
  __shared__ short Ah[32][36], Al[32][36];       // 4608 B
  __shared__ short Bh[64][36], Bl[64][36];       // 9216 B
  __shared__ int srcs[32];
  __shared__ float gains[32];
  int e = blockIdx.y;
  int rank = blockIdx.z;
  int l = e*2 + rank;
  int nrows = cnt[l];
  int r0 = blockIdx.x * 32;
  if (r0 >= nrows) return;
  int t = threadIdx.x;
  int w = t >> 6, lane = t & 63;
  int wm = w >> 1, wn = w & 1;          // wm: 16-row half, wn: 32-col half
  if (t < 32) {
    int rr = r0 + t;
    srcs[t]  = (rr < nrows) ? rec_src [(size_t)l*NSLOT + rr] : -1;
    gains[t] = (rr < nrows) ? rec_gain[(size_t)l*NSLOT + rr] : 0.f;
  }
  __syncthreads();
  const size_t wofs = (size_t)e*DM*DM;
  int tr = t >> 3, tq = t & 7;          // A staging: row 0..31, 4-short oct
  int bn = t >> 2, bq = t & 3;          // B staging: col 0..63, 8-short quarter
  int mysrc = srcs[tr];

  // ================= layer 1: hid = gelu(x @ w1) =================
  for (int n0 = 0; n0 < 512; n0 += 64) {
    f32x4 acc[2];
    acc[0] = (f32x4){0.f,0.f,0.f,0.f};
    acc[1] = (f32x4){0.f,0.f,0.f,0.f};
    for (int k0 = 0; k0 < 512; k0 += 32) {
      {
        s16x4 hv = (s16x4)(short)0, lv = (s16x4)(short)0;
        if (mysrc >= 0) {
          size_t ab = (size_t)mysrc*DM + k0 + tq*4;
          hv = *(const s16x4*)&Xh[ab];
          lv = *(const s16x4*)&Xl[ab];
        }
        *(s16x4*)&Ah[tr][tq*4] = hv;
        *(s16x4*)&Al[tr][tq*4] = lv;
      }
      {
        size_t bb = wofs + (size_t)(n0 + bn)*DM + k0 + bq*8;
        *(s16x8*)&Bh[bn][bq*8] = *(const s16x8*)&W1h[bb];
        *(s16x8*)&Bl[bn][bq*8] = *(const s16x8*)&W1l[bb];
      }
      __syncthreads();
      int cofs = (lane >> 4)*8;
      int ar = wm*16 + (lane & 15);
      s16x8 ahf = *(const s16x8*)&Ah[ar][cofs];
      s16x8 alf = *(const s16x8*)&Al[ar][cofs];
#pragma unroll
      for (int fn = 0; fn < 2; fn++) {
        int br = wn*32 + fn*16 + (lane & 15);
        s16x8 bhf = *(const s16x8*)&Bh[br][cofs];
        s16x8 blf = *(const s16x8*)&Bl[br][cofs];
        acc[fn] = __builtin_amdgcn_mfma_f32_16x16x32_bf16(ahf, bhf, acc[fn], 0, 0, 0);
        acc[fn] = __builtin_amdgcn_mfma_f32_16x16x32_bf16(alf, bhf, acc[fn], 0, 0, 0);
        acc[fn] = __builtin_amdgcn_mfma_f32_16x16x32_bf16(ahf, blf, acc[fn], 0, 0, 0);
      }
      __syncthreads();
    }
#pragma unroll
    for (int jj = 0; jj < 4; jj++) {
      int row = wm*16 + (lane >> 4)*4 + jj;
#pragma unroll
      for (int fn = 0; fn < 2; fn++) {
        int col = n0 + wn*32 + fn*16 + (lane & 15);
        hid[row][col] = split_pk(gelu_tanh(acc[fn][jj]));
      }
    }
  }
  __syncthreads();

  // ================= layer 2: out = hid @ w2; Y[src] += gain*out (atomic) =================
  for (int n0 = 0; n0 < 512; n0 += 64) {
    f32x4 acc[2];
    acc[0] = (f32x4){0.f,0.f,0.f,0.f};
    acc[1] = (f32x4){0.f,0.f,0.f,0.f};
    for (int k0 = 0; k0 < 512; k0 += 32) {
      {
        size_t bb = wofs + (size_t)(n0 + bn)*DM + k0 + bq*8;
        *(s16x8*)&Bh[bn][bq*8] = *(const s16x8*)&W2h[bb];
        *(s16x8*)&Bl[bn][bq*8] = *(const s16x8*)&W2l[bb];
      }
      __syncthreads();
      int cofs = (lane >> 4)*8;
      int ar = wm*16 + (lane & 15);
      u32x4 pa  = *(const u32x4*)&hid[ar][k0 + cofs];
      u32x4 pb2 = *(const u32x4*)&hid[ar][k0 + cofs + 4];
      s16x8 hv, lv;
#pragma unroll
      for (int q = 0; q < 4; q++) {
        hv[q]   = (short)(pa[q] & 0xffffu);  lv[q]   = (short)(pa[q] >> 16);
        hv[q+4] = (short)(pb2[q] & 0xffffu); lv[q+4] = (short)(pb2[q] >> 16);
      }
#pragma unroll
      for (int fn = 0; fn < 2; fn++) {
        int br = wn*32 + fn*16 + (lane & 15);
        s16x8 bhf = *(const s16x8*)&Bh[br][cofs];
        s16x8 blf = *(const s16x8*)&Bl[br][cofs];
        acc[fn] = __builtin_amdgcn_mfma_f32_16x16x32_bf16(hv, bhf, acc[fn], 0, 0, 0);
        acc[fn] = __builtin_amdgcn_mfma_f32_16x16x32_bf16(lv, bhf, acc[fn], 0, 0, 0);
        acc[fn] = __builtin_amdgcn_mfma_f32_16x16x32_bf16(hv, blf, acc[fn], 0, 0, 0);
      }
      __syncthreads();
    }
#pragma unroll
    for (int jj = 0; jj < 4; jj++) {
      int row = wm*16 + (lane >> 4)*4 + jj;
      int src = srcs[row];
      float g = gains[row];
      if (src >= 0) {
#pragma unroll
        for (int fn = 0; fn < 2; fn++) {
          int col = n0 + wn*32 + fn*16 + (lane & 15);
          atomicAdd(&Y[(size_t)src*DM + col], g * acc[fn][jj]);
        }
      }
    }
  }
}

// ---------------- classifier epilogue ----------------
__global__ __launch_bounds__(256) void k_h1norm(
    float* __restrict__ H, const float* __restrict__ bias, const float* __restrict__ w) {
  int r = blockIdx.x, t = threadIdx.x;
  size_t base = (size_t)r*1000;
  float v[4]; float ss = 0.f;
#pragma unroll
  for (int i = 0; i < 4; i++) {
    int c = t + i*256;
    float x = 0.f;
    if (c < 1000) { x = fmaxf(H[base+c] + bias[c], 0.f); }
    v[i] = x; ss += x*x;
  }
#pragma unroll
  for (int o = 32; o; o >>= 1) ss += __shfl_xor(ss, o);
  __shared__ float red[4];
  if ((t & 63) == 0) red[t>>6] = ss;
  __syncthreads();
  float tot = red[0]+red[1]+red[2]+red[3];
  float sc = rsqrtf(tot * 0.001f + 1e-6f);
#pragma unroll
  for (int i = 0; i < 4; i++) {
    int c = t + i*256;
    if (c < 1000) H[base+c] = v[i]*sc*w[c];
  }
}

__global__ __launch_bounds__(128) void k_h2(
    const float* __restrict__ H1, const float* __restrict__ W2c,
    const float* __restrict__ b2, const float* __restrict__ rms2,
    float* __restrict__ H2) {
  __shared__ float hrow[1000];
  __shared__ float sq[128];
  int r = blockIdx.x, t = threadIdx.x;
  for (int c = t; c < 1000; c += 128) hrow[c] = H1[(size_t)r*1000+c];
  __syncthreads();
  float acc = 0.f;
  if (t < 100) {
    for (int k = 0; k < 1000; k++) acc += hrow[k]*W2c[k*100+t];
    acc = fmaxf(acc + b2[t], 0.f);
  }
  sq[t] = (t < 100) ? acc*acc : 0.f;
  __syncthreads();
  if (t < 64) sq[t] += sq[t+64];
  __syncthreads();
  if (t == 0) { float s = 0.f; for (int i = 0; i < 64; i++) s += sq[i]; sq[0] = s; }
  __syncthreads();
  float sc = rsqrtf(sq[0]*0.01f + 1e-6f);
  if (t < 100) H2[(size_t)r*100+t] = acc*sc*rms2[t];
}

__global__ __launch_bounds__(256) void k_out(
    const float* __restrict__ H2, const float* __restrict__ w3,
    const float* __restrict__ b3, float* __restrict__ out) {
  int b = blockIdx.x*256 + threadIdx.x;
  if (b >= NB) return;
  float acc = b3[0];
  for (int k = 0; k < 100; k++) acc += H2[(size_t)b*100+k]*w3[k];
  out[b] = acc;
}

extern "C" void kernel_launch(void* const* d_in, const int* in_sizes, int n_in,
                              void* d_out, int out_size, void* d_ws, size_t ws_size,
                              hipStream_t stream) {
  const int*   ta   = (const int*)d_in[0];
  const int*   tb   = (const int*)d_in[1];
  const int*   tp   = (const int*)d_in[2];
  const float* Wa   = (const float*)d_in[3];
  const float* Wb   = (const float*)d_in[4];
  const float* Wp   = (const float*)d_in[5];
  const float* AW   = (const float*)d_in[6];
  const float* rmsd = (const float*)d_in[7];
  const float* Wg   = (const float*)d_in[8];
  const float* W1   = (const float*)d_in[9];
  const float* W2   = (const float*)d_in[10];
  const float* cw1  = (const float*)d_in[11];
  const float* cb1  = (const float*)d_in[12];
  const float* rms1 = (const float*)d_in[13];
  const float* cw2  = (const float*)d_in[14];
  const float* cb2  = (const float*)d_in[15];
  const float* rms2 = (const float*)d_in[16];
  const float* cw3  = (const float*)d_in[17];
  const float* cb3  = (const float*)d_in[18];
  float* out = (float*)d_out;

  const size_t WMAT = (size_t)DM*DM;        // 262,144

  char* ws = (char*)d_ws;
  float*   X   = (float*)ws;                               // 159.4 MB f32 residual (exact)
  ushortt* Xh  = (ushortt*)(ws + 159383552ULL);            // 79.7 MB
  ushortt* Xl  = (ushortt*)(ws + 239075328ULL);            // 79.7 MB
  float*   Q0  = (float*)(ws + 318767104ULL);              // 119.5 MB QKV chunk scratch
  // Aliases inside Q0 (used only after encoders are done):
  ushortt* W1h = (ushortt*)(ws + 318767104ULL);            // k-major planes, 8.39 MB each
  ushortt* W1l = W1h + 16*WMAT;
  ushortt* W2h = W1l + 16*WMAT;
  ushortt* W2l = W2h + 16*WMAT;                            // ends +33.55 MB
  float*   P   = (float*)(ws + 318767104ULL + 33554432ULL);// classifier partials 32.8 MB
  // cw1 k-major planes alias the (dead-after-final-split) X region:
  ushortt* CW1h = (ushortt*)ws;                            // 77.8 MB
  ushortt* CW1l = CW1h + (size_t)38912*1000;               // ends 155.6 MB < 159.4 ✓
  ushortt* AWh = (ushortt*)(ws + 438304768ULL);            // k-major planes
  ushortt* AWl = AWh + 16*WMAT;                            // ends 455,081,984
  int*     rec_src  = (int*)(ws + 455081984ULL);
  float*   rec_gain = (float*)(ws + 457572352ULL);
  int*     cnt      = (int*)(ws + 460062720ULL);
  float*   h1       = (float*)(ws + 460062976ULL);
  float*   h2       = (float*)(ws + 464158976ULL);         // ends ~464.6 MB

  // 0. relayout attention weights -> k-major hi/lo planes
  k_relayout<<<dim3(8,8,16), 256, 0, stream>>>(AW, AWh, AWl, 512, 512);

  // 1. embedding + PE -> X (f32) + planes
  k_embed<<<dim3((int)((NELM+255)/256)), 256, 0, stream>>>(ta,tb,tp,Wa,Wb,Wp,X,Xh,Xl);

  // 2-4. per-branch encoders, 2 batch-chunks of 512
  const int segs[3]  = {SSA, SSB, SSP};
  const int boffs[3] = {0, SSA, SSA+SSB};
  for (int br = 0; br < 3; br++) {
    int seg = segs[br], boff = boffs[br];
    const int CHB = 512;
    int M = CHB*seg;
    long long qst = (long long)M*DM;
    float* Qr = Q0; float* Kr = Q0 + qst; float* Vr = Q0 + 2*qst;
    for (int ch = 0; ch < NB/CHB; ch++) {
      int cb0 = ch*CHB;
      k_mfma<0,1,1><<<dim3(M/128,12,1),256,0,stream>>>(
          Xh, Xl, AWh + (size_t)br*4*WMAT, AWl + (size_t)br*4*WMAT, Q0,
          1536,512, 512,512,0,  seg,NS,boff,seg,cb0, (long long)WMAT,9, qst, 0);
      k_attn2<<<dim3(CHB,NH),256,0,stream>>>(Qr, Kr, Vr, seg);
      k_mfma<1,0,1><<<dim3(M/128,4,1),256,0,stream>>>(
          (const ushortt*)Qr, (const ushortt*)Qr + (size_t)seg*64,
          AWh + (size_t)(br*4+3)*WMAT, AWl + (size_t)(br*4+3)*WMAT, Vr,
          512,512, 0,512,512,  seg,seg,0,seg,0, 0,30, 0, 0);
      k_addnorm<<<M,256,0,stream>>>(X, Xh, Xl, Vr, rmsd, seg, boff, cb0);
    }
  }

  // 5. full-sequence encoder, 4 batch-chunks of 256
  {
    const int CH = 256;
    int M = CH*NS;                       // 19456
    long long qst = (long long)M*DM;
    float* Qr = Q0; float* Kr = Q0 + qst; float* Vr = Q0 + 2*qst;
    for (int ch = 0; ch < NB/CH; ch++) {
      int cb0 = ch*CH;
      k_mfma<0,1,1><<<dim3(M/128,12,1),256,0,stream>>>(
          Xh, Xl, AWh + (size_t)12*WMAT, AWl + (size_t)12*WMAT, Q0,
          1536,512, 512,512,0,  NS,NS,0,NS,cb0, (long long)WMAT,9, qst, 0);
      k_attn2<<<dim3(CH,NH),256,0,stream>>>(Qr, Kr, Vr, NS);
      k_mfma<1,0,1><<<dim3(M/128,4,1),256,0,stream>>>(
          (const ushortt*)Qr, (const ushortt*)Qr + (size_t)NS*64,
          AWh + (size_t)15*WMAT, AWl + (size_t)15*WMAT, Vr,
          512,512, 0,512,512,  NS,NS,0,NS,0, 0,30, 0, 0);
      k_addnorm<<<M,256,0,stream>>>(X, Xh, Xl, Vr, rmsd, NS, 0, cb0);
    }
  }

  // 6. MoE: expert weights -> k-major planes in dead Q0; route on f32 X; both ranks in one launch
  k_relayout<<<dim3(8,8,16), 256, 0, stream>>>(W1, W1h, W1l, 512, 512);
  k_relayout<<<dim3(8,8,16), 256, 0, stream>>>(W2, W2h, W2l, 512, 512);
  hipError_t e1 = hipMemsetAsync(cnt, 0, NE*2*sizeof(int), stream); (void)e1;
  k_route<<<NB,256,0,stream>>>(X, Wg, rec_src, rec_gain, cnt);
  k_expert_mfma<<<dim3((NSLOT+31)/32, NE, 2),256,0,stream>>>(Xh, Xl, W1h, W1l, W2h, W2l, X, rec_src, rec_gain, cnt);

  // 7. classifier: split post-MoE X -> planes (X now dead), cw1 -> k-major planes in X region,
  //    split-K GEMM (MW=4 register cap), reduce, epilogue
  k_split_planes<<<dim3((int)((NELM+255)/256)), 256, 0, stream>>>(X, Xh, Xl, (int)NELM);
  k_relayout<<<dim3(608,16,1), 256, 0, stream>>>(cw1, CW1h, CW1l, 38912, 1000);
  k_mfma<0,0,4><<<dim3(NB/128,(1000+127)/128,KSPLIT),256,0,stream>>>(
      Xh, Xl, CW1h, CW1l, P,
      1000, (NS*DM)/KSPLIT, NS*DM, NS*DM, 1000,  NB,0,0,1,0, 0,30, 0, (long long)NB*1000);
  k_ksum<<<dim3((NB*1000+255)/256),256,0,stream>>>(P, h1);
  k_h1norm<<<NB,256,0,stream>>>(h1, cb1, rms1);
  k_h2<<<NB,128,0,stream>>>(h1, cw2, cb2, rms2, h2);
  k_out<<<dim3((NB+255)/256),256,0,stream>>>(h2, cw3, cb3, out);
}

// Round 20
// 5306.416 us; speedup vs baseline: 1.0083x; 1.0083x over previous
//
#include <hip/hip_runtime.h>
#include <math.h>

#define NB 1024
#define NS 76
#define SSA 34
#define SSB 28
#define SSP 14
#define DM 512
#define NH 8
#define DH 64
#define NE 16
#define CAP 19
#define NSLOT (NB*CAP)
#define KSPLIT 8
#define NELM ((size_t)NB*NS*DM)

typedef unsigned short ushortt;
typedef short s16x4 __attribute__((ext_vector_type(4)));
typedef short s16x8 __attribute__((ext_vector_type(8)));
typedef float f32x4 __attribute__((ext_vector_type(4)));
typedef unsigned int u32x4 __attribute__((ext_vector_type(4)));

__device__ __forceinline__ ushortt f2bf(float f) {
  union { float f; unsigned int u; } v; v.f = f;
  unsigned int u = v.u;
  u += 0x7fffu + ((u >> 16) & 1u);
  return (ushortt)(u >> 16);
}
__device__ __forceinline__ float bf2f(ushortt s) {
  union { unsigned int u; float f; } v; v.u = ((unsigned int)s) << 16;
  return v.f;
}
__device__ __forceinline__ void split2(float v, ushortt& h, ushortt& l) {
  h = f2bf(v);
  l = f2bf(v - bf2f(h));
}
__device__ __forceinline__ unsigned int split_pk(float v) {
  ushortt h, l; split2(v, h, l);
  return ((unsigned int)l << 16) | (unsigned int)h;
}
__device__ __forceinline__ float gelu_tanh(float x) {
  float x3 = x*x*x;
  return 0.5f*x*(1.0f + tanhf(0.7978845608028654f*(x + 0.044715f*x3)));
}

// ---------------- embedding + sinusoidal PE -> X f32 + Xh/Xl planes ----------------
__global__ __launch_bounds__(256) void k_embed(
    const int* __restrict__ ta, const int* __restrict__ tb, const int* __restrict__ tp,
    const float* __restrict__ Wa, const float* __restrict__ Wb, const float* __restrict__ Wp,
    float* __restrict__ X, ushortt* __restrict__ Xh, ushortt* __restrict__ Xl) {
  int idx = blockIdx.x * 256 + threadIdx.x;
  if (idx >= NB*NS*DM) return;
  int d = idx & (DM-1);
  int bs = idx >> 9;
  int s = bs % NS, b = bs / NS;
  int sl, tok; const float* W;
  if (s < SSA)          { sl = s;         tok = ta[b*SSA+sl]; W = Wa; }
  else if (s < SSA+SSB) { sl = s-SSA;     tok = tb[b*SSB+sl]; W = Wb; }
  else                  { sl = s-SSA-SSB; tok = tp[b*SSP+sl]; W = Wp; }
  float dv = expf((float)(d & ~1) * (-9.210340371976184f/512.0f));
  float ang = (float)sl * dv;
  float pe = (d & 1) ? cosf(ang) : sinf(ang);
  float v = W[(size_t)tok*DM + d] + pe;
  X[idx] = v;
  ushortt h, l; split2(v, h, l);
  Xh[idx] = h; Xl[idx] = l;
}

// ---------------- f32 -> hi/lo plane split (same layout) ----------------
__global__ __launch_bounds__(256) void k_split_planes(
    const float* __restrict__ in, ushortt* __restrict__ hp, ushortt* __restrict__ lp, int n) {
  int i = blockIdx.x * 256 + threadIdx.x;
  if (i < n) { ushortt h, l; split2(in[i], h, l); hp[i] = h; lp[i] = l; }
}

// ---------------- weight relayout: f32 [mat][K][N] -> k-major hi/lo planes [mat][N][K] ----------------
__global__ __launch_bounds__(256) void k_relayout(
    const float* __restrict__ in, ushortt* __restrict__ oh, ushortt* __restrict__ ol,
    int K, int N) {
  __shared__ float tile[64][65];
  long long base = (long long)blockIdx.z * K * N;
  int k0 = blockIdx.x * 64, n0 = blockIdx.y * 64;
  int t = threadIdx.x;
  int tx = t & 63, ty = t >> 6;
#pragma unroll
  for (int i = 0; i < 64; i += 4) {
    int k = k0 + ty + i, n = n0 + tx;
    if (n < N) tile[ty + i][tx] = in[base + (long long)k*N + n];
  }
  __syncthreads();
#pragma unroll
  for (int i = 0; i < 64; i += 4) {
    int n = n0 + ty + i, k = k0 + tx;
    if (n < N) {
      ushortt h, l; split2(tile[tx][ty + i], h, l);
      long long o = base + (long long)n*K + k;
      oh[o] = h; ol[o] = l;
    }
  }
}

// ---------------- split-plane MFMA GEMM, 128x128 tile, BK=32, 3 MFMA/frag ----------------
template<int AHEAD, int CM, int MW>
__global__ __launch_bounds__(256, MW) void k_mfma(
    const ushortt* __restrict__ Ahg, const ushortt* __restrict__ Alg,
    const ushortt* __restrict__ Bhg, const ushortt* __restrict__ Blg,
    float* __restrict__ Cp,
    int N, int K, int lda, int KB, int ldc,
    int rpg, int pitch, int roff, int seg, int cb0,
    long long bstride, int bshift, long long qst, long long csplit) {
  __shared__ short Ah[128][36], Al[128][36], Bh[128][36], Bl[128][36];
  int t = threadIdx.x;
  int m0 = blockIdx.x * 128, n0 = blockIdx.y * 128;
  int kz = blockIdx.z;
  long long koff = (long long)kz * K;
  int w = t >> 6, lane = t & 63;
  int wm = w >> 1, wn = w & 1;
  int arow = t >> 1, ahalf = t & 1;
  int am = m0 + arow;
  int abi = am / rpg, asl = am - abi*rpg;
  size_t afl = 0;
  if (AHEAD == 0) afl = ((size_t)(abi + cb0)*pitch + roff + asl)*lda + (size_t)koff;
  int bn = t & 127, bkh = t >> 7;
  int gn = n0 + bn;
  const ushortt* Bh_c = nullptr; const ushortt* Bl_c = nullptr;
  if (gn < N) {
    int j = gn >> bshift, col = gn - (j << bshift);
    long long bb = (long long)j*bstride + (long long)col*KB + koff;
    Bh_c = Bhg + bb; Bl_c = Blg + bb;
  }
  f32x4 acc[4][4];
#pragma unroll
  for (int i = 0; i < 4; i++)
#pragma unroll
    for (int j = 0; j < 4; j++) acc[i][j] = (f32x4){0.f,0.f,0.f,0.f};

  for (int k0 = 0; k0 < K; k0 += 32) {
    // ---- stage A: contiguous plane copies ----
    {
      size_t ab;
      if (AHEAD == 0) ab = afl + k0 + ahalf*16;
      else {
        int c = k0 + ahalf*16;
        ab = (size_t)(abi*8 + (c >> 6))*((size_t)seg*128) + (size_t)asl*64 + (c & 63);
      }
      s16x8 h0 = *(const s16x8*)&Ahg[ab];
      s16x8 h1 = *(const s16x8*)&Ahg[ab + 8];
      s16x8 l0 = *(const s16x8*)&Alg[ab];
      s16x8 l1 = *(const s16x8*)&Alg[ab + 8];
      *(s16x8*)&Ah[arow][ahalf*16]     = h0;
      *(s16x8*)&Ah[arow][ahalf*16 + 8] = h1;
      *(s16x8*)&Al[arow][ahalf*16]     = l0;
      *(s16x8*)&Al[arow][ahalf*16 + 8] = l1;
    }
    // ---- stage B: contiguous plane copies (k-major) ----
    {
      s16x8 h0 = (s16x8)(short)0, h1v = (s16x8)(short)0;
      s16x8 l0 = (s16x8)(short)0, l1v = (s16x8)(short)0;
      if (Bh_c) {
        h0  = *(const s16x8*)&Bh_c[k0 + bkh*16];
        h1v = *(const s16x8*)&Bh_c[k0 + bkh*16 + 8];
        l0  = *(const s16x8*)&Bl_c[k0 + bkh*16];
        l1v = *(const s16x8*)&Bl_c[k0 + bkh*16 + 8];
      }
      *(s16x8*)&Bh[bn][bkh*16]     = h0;
      *(s16x8*)&Bh[bn][bkh*16 + 8] = h1v;
      *(s16x8*)&Bl[bn][bkh*16]     = l0;
      *(s16x8*)&Bl[bn][bkh*16 + 8] = l1v;
    }
    __syncthreads();
    s16x8 ahf[4], alf[4];
#pragma unroll
    for (int fm = 0; fm < 4; fm++) {
      int r = wm*64 + fm*16 + (lane & 15);
      int cofs = (lane >> 4)*8;
      ahf[fm] = *(const s16x8*)&Ah[r][cofs];
      alf[fm] = *(const s16x8*)&Al[r][cofs];
    }
#pragma unroll
    for (int fn = 0; fn < 4; fn++) {
      int r = wn*64 + fn*16 + (lane & 15);
      int cofs = (lane >> 4)*8;
      s16x8 bhf = *(const s16x8*)&Bh[r][cofs];
      s16x8 blf = *(const s16x8*)&Bl[r][cofs];
#pragma unroll
      for (int fm = 0; fm < 4; fm++) {
        acc[fm][fn] = __builtin_amdgcn_mfma_f32_16x16x32_bf16(ahf[fm], bhf, acc[fm][fn], 0, 0, 0);
        acc[fm][fn] = __builtin_amdgcn_mfma_f32_16x16x32_bf16(alf[fm], bhf, acc[fm][fn], 0, 0, 0);
        acc[fm][fn] = __builtin_amdgcn_mfma_f32_16x16x32_bf16(ahf[fm], blf, acc[fm][fn], 0, 0, 0);
      }
    }
    __syncthreads();
  }
  // ---- epilogue ----
#pragma unroll
  for (int fm = 0; fm < 4; fm++) {
#pragma unroll
    for (int jj = 0; jj < 4; jj++) {
      int mrow = m0 + wm*64 + fm*16 + (lane >> 4)*4 + jj;
      int bi = mrow / rpg, sl = mrow - bi*rpg;
#pragma unroll
      for (int fn = 0; fn < 4; fn++) {
        int ncol = n0 + wn*64 + fn*16 + (lane & 15);
        float vv = acc[fm][fn][jj];
        if (CM == 0) {
          if (ncol < N) Cp[(long long)kz*csplit + (size_t)(bi*pitch + roff + sl)*ldc + ncol] = vv;
        } else {
          int j = ncol >> 9, rem = ncol & 511;
          int hh = rem >> 6, dd = rem & 63;
          Cp[(long long)j*qst + ((size_t)(bi*8 + hh)*seg + sl)*64 + dd] = vv;
        }
      }
    }
  }
}

// ---------------- k-split reduce ----------------
__global__ __launch_bounds__(256) void k_ksum(
    const float* __restrict__ P, float* __restrict__ h1) {
  int i = blockIdx.x * 256 + threadIdx.x;
  if (i >= NB*1000) return;
  float s = 0.f;
#pragma unroll
  for (int z = 0; z < KSPLIT; z++) s += P[(size_t)z*NB*1000 + i];
  h1[i] = s;
}

// ---------------- attention core per (b,h): f32 QKV in, hi/lo planes over own Q slice ----------------
__global__ __launch_bounds__(256) void k_attn2(
    float* __restrict__ Qb, const float* __restrict__ Kb, const float* __restrict__ Vb, int seg) {
  __shared__ float Qs[NS][65], Ks[NS][65], Vs[NS][65];
  __shared__ float pb[4][128];
  int b = blockIdx.x, h = blockIdx.y;
  size_t base = ((size_t)(b*8 + h)) * seg * 64;
  int t = threadIdx.x, w = t >> 6, lane = t & 63;
  for (int i = t; i < seg*64; i += 256) {
    int r = i >> 6, d = i & 63;
    Qs[r][d] = Qb[base + i];
    Ks[r][d] = Kb[base + i];
    Vs[r][d] = Vb[base + i];
  }
  __syncthreads();
  ushortt* Ou = (ushortt*)Qb;      // write planes into own (dead) Q slice
  size_t ub2 = 2*base;
  for (int qi = w; qi < seg; qi += 4) {
    float s1 = -1e30f, s2 = -1e30f;
    int j1 = lane, j2 = lane + 64;
    if (j1 < seg) {
      float acc = 0.f;
#pragma unroll
      for (int d = 0; d < DH; d++) acc += Qs[qi][d]*Ks[j1][d];
      s1 = acc * 0.125f;
    }
    if (j2 < seg) {
      float acc = 0.f;
#pragma unroll
      for (int d = 0; d < DH; d++) acc += Qs[qi][d]*Ks[j2][d];
      s2 = acc * 0.125f;
    }
    float m = fmaxf(s1, s2);
#pragma unroll
    for (int o = 32; o; o >>= 1) m = fmaxf(m, __shfl_xor(m, o));
    float p1 = (j1 < seg) ? expf(s1 - m) : 0.f;
    float p2 = (j2 < seg) ? expf(s2 - m) : 0.f;
    float l = p1 + p2;
#pragma unroll
    for (int o = 32; o; o >>= 1) l += __shfl_xor(l, o);
    float inv = 1.f / l;
    pb[w][lane] = p1 * inv;
    pb[w][lane + 64] = p2 * inv;
    float o = 0.f;
    for (int j = 0; j < seg; j++) o += pb[w][j] * Vs[j][lane];
    ushortt hh, ll; split2(o, hh, ll);
    Ou[ub2 + (size_t)qi*64 + lane] = hh;
    Ou[ub2 + (size_t)seg*64 + (size_t)qi*64 + lane] = ll;
  }
}

// ---------------- residual add + RMSNorm: X f32 exact, planes emitted ----------------
__global__ __launch_bounds__(256) void k_addnorm(
    float* __restrict__ X, ushortt* __restrict__ Xh, ushortt* __restrict__ Xl,
    const float* __restrict__ U, const float* __restrict__ w,
    int seg, int boff, int cb0) {
  int r = blockIdx.x, t = threadIdx.x;
  int b = r / seg + cb0, s = r - (r / seg)*seg;
  size_t xb = ((size_t)b*NS + boff + s)*DM;
  size_t ub = (size_t)r*DM;
  float v0 = X[xb+t] + U[ub+t];
  float v1 = X[xb+t+256] + U[ub+t+256];
  float ss = v0*v0 + v1*v1;
#pragma unroll
  for (int o = 32; o; o >>= 1) ss += __shfl_xor(ss, o);
  __shared__ float red[4];
  if ((t & 63) == 0) red[t>>6] = ss;
  __syncthreads();
  float tot = red[0]+red[1]+red[2]+red[3];
  float sc = rsqrtf(tot * (1.f/512.f) + 1e-6f);
  float o0 = v0*sc*w[t], o1 = v1*sc*w[t+256];
  X[xb+t] = o0; X[xb+t+256] = o1;
  ushortt h, l;
  split2(o0, h, l); Xh[xb+t] = h; Xl[xb+t] = l;
  split2(o1, h, l); Xh[xb+t+256] = h; Xl[xb+t+256] = l;
}

// ---------------- MoE routing: gl matmul + parallel scatter ----------------
__global__ __launch_bounds__(256) void k_route(
    const float* __restrict__ X, const float* __restrict__ Wg,
    int* __restrict__ rec_src, float* __restrict__ rec_gain, int* __restrict__ cnt) {
  __shared__ float gl[NS][NE];
  __shared__ float WgT[NE][DM + 1];
  __shared__ float4 Xs[NS][16];
  __shared__ float g1s[NS], g2s[NS];
  __shared__ int i1s[NS], i2s[NS];
  int b = blockIdx.x, t = threadIdx.x;
  for (int i = t; i < DM*NE; i += 256) {
    int k = i >> 4, e = i & 15;
    WgT[e][k] = Wg[i];
  }
  int e = t & 15;
  int srow = t >> 4;
  float a0[5], a1[5], a2[5], a3[5];
#pragma unroll
  for (int j = 0; j < 5; j++) { a0[j]=0.f; a1[j]=0.f; a2[j]=0.f; a3[j]=0.f; }
  __syncthreads();
  for (int ch = 0; ch < 8; ch++) {
    for (int i = t; i < NS*16; i += 256) {
      int s = i >> 4, f = i & 15;
      Xs[s][f] = *(const float4*)&X[((size_t)b*NS + s)*DM + ch*64 + f*4];
    }
    __syncthreads();
#pragma unroll
    for (int j = 0; j < 5; j++) {
      int s = srow + j*16;
      if (s < NS) {
        const float* wr = &WgT[e][ch*64];
        const float4* xr = &Xs[s][0];
#pragma unroll
        for (int k = 0; k < 64; k += 8) {
          float4 xa = xr[k >> 2];
          float4 xb = xr[(k >> 2) + 1];
          a0[j] += xa.x*wr[k]   + xb.x*wr[k+4];
          a1[j] += xa.y*wr[k+1] + xb.y*wr[k+5];
          a2[j] += xa.z*wr[k+2] + xb.z*wr[k+6];
          a3[j] += xa.w*wr[k+3] + xb.w*wr[k+7];
        }
      }
    }
    __syncthreads();
  }
#pragma unroll
  for (int j = 0; j < 5; j++) {
    int s = srow + j*16;
    if (s < NS) gl[s][e] = (a0[j] + a1[j]) + (a2[j] + a3[j]);
  }
  __syncthreads();
  if (t < NS) {
    float mx = -1e30f;
#pragma unroll
    for (int ee = 0; ee < NE; ee++) mx = fmaxf(mx, gl[t][ee]);
    float sum = 0.f;
#pragma unroll
    for (int ee = 0; ee < NE; ee++) sum += expf(gl[t][ee]-mx);
    int i1 = 0; float l1 = gl[t][0];
#pragma unroll
    for (int ee = 1; ee < NE; ee++) if (gl[t][ee] > l1) { l1 = gl[t][ee]; i1 = ee; }
    int i2 = -1; float l2 = -1e30f;
#pragma unroll
    for (int ee = 0; ee < NE; ee++) if (ee != i1 && gl[t][ee] > l2) { l2 = gl[t][ee]; i2 = ee; }
    float g1 = expf(l1-mx)/sum, g2 = expf(l2-mx)/sum;
    float den = g1 + g2 + 1e-9f;
    g1s[t] = g1/den; g2s[t] = g2/den;
    i1s[t] = i1; i2s[t] = i2;
  }
  __syncthreads();
  // parallel scatter: one thread per (expert, rank) list, ONE atomic each
  if (t < 32) {
    int ee = t >> 1, rank = t & 1;
    int n1 = 0;
    for (int s = 0; s < NS; s++) if (i1s[s] == ee) n1++;
    if (rank == 0) {
      int nloc = n1 < CAP ? n1 : CAP;
      if (nloc > 0) {
        int basei = atomicAdd(&cnt[ee*2+0], nloc);
        size_t lb = (size_t)(ee*2+0)*NSLOT + basei;
        int p = 0;
        for (int s = 0; s < NS && p < nloc; s++) {
          if (i1s[s] == ee) {
            rec_src[lb + p] = b*NS + s;
            rec_gain[lb + p] = g1s[s];
            p++;
          }
        }
      }
    } else {
      int c1 = n1 < CAP ? n1 : CAP;
      int lim = CAP - c1; if (lim < 0) lim = 0;
      int n2 = 0;
      for (int s = 0; s < NS; s++) if (i2s[s] == ee) n2++;
      int nloc = n2 < lim ? n2 : lim;
      if (nloc > 0) {
        int basei = atomicAdd(&cnt[ee*2+1], nloc);
        size_t lb = (size_t)(ee*2+1)*NSLOT + basei;
        int p = 0;
        for (int s = 0; s < NS && p < nloc; s++) {
          if (i2s[s] == ee) {
            rec_src[lb + p] = b*NS + s;
            rec_gain[lb + p] = g2s[s];
            p++;
          }
        }
      }
    }
  }
}

// ---------------- fused expert MLP, 32-row tiles; both ranks in one launch (z=rank), atomic scatter ----------------
__global__ __launch_bounds__(256, 2) void k_expert_mfma(
    const ushortt* __restrict__ Xh, const ushortt* __restrict__ Xl,
    const ushortt* __restrict__ W1h, const ushortt* __restrict__ W1l,
    const ushortt* __restrict__ W2h, const ushortt* __restrict__ W2l,
    float* __restrict__ Y,
    const int* __restrict__ rec_src, const float* __restrict__ rec_gain,
    const int* __restrict__ cnt) {
  __shared__ unsigned int hid[32][516];          // 66048 B (round-18 best layout)
  __shared__ short Ah[32][36], Al[32][36];       // 4608 B
  __shared__ short Bh[64][36], Bl[64][36];       // 9216 B
  __shared__ int srcs[32];
  __shared__ float gains[32];
  int e = blockIdx.y;
  int rank = blockIdx.z;
  int l = e*2 + rank;
  int nrows = cnt[l];
  int r0 = blockIdx.x * 32;
  if (r0 >= nrows) return;
  int t = threadIdx.x;
  int w = t >> 6, lane = t & 63;
  int wm = w >> 1, wn = w & 1;          // wm: 16-row half, wn: 32-col half
  if (t < 32) {
    int rr = r0 + t;
    srcs[t]  = (rr < nrows) ? rec_src [(size_t)l*NSLOT + rr] : -1;
    gains[t] = (rr < nrows) ? rec_gain[(size_t)l*NSLOT + rr] : 0.f;
  }
  __syncthreads();
  const size_t wofs = (size_t)e*DM*DM;
  int tr = t >> 3, tq = t & 7;          // A staging: row 0..31, 4-short oct
  int bn = t >> 2, bq = t & 3;          // B staging: col 0..63, 8-short quarter
  int mysrc = srcs[tr];

  // ================= layer 1: hid = gelu(x @ w1) =================
  for (int n0 = 0; n0 < 512; n0 += 64) {
    f32x4 acc[2];
    acc[0] = (f32x4){0.f,0.f,0.f,0.f};
    acc[1] = (f32x4){0.f,0.f,0.f,0.f};
    for (int k0 = 0; k0 < 512; k0 += 32) {
      {
        s16x4 hv = (s16x4)(short)0, lv = (s16x4)(short)0;
        if (mysrc >= 0) {
          size_t ab = (size_t)mysrc*DM + k0 + tq*4;
          hv = *(const s16x4*)&Xh[ab];
          lv = *(const s16x4*)&Xl[ab];
        }
        *(s16x4*)&Ah[tr][tq*4] = hv;
        *(s16x4*)&Al[tr][tq*4] = lv;
      }
      {
        size_t bb = wofs + (size_t)(n0 + bn)*DM + k0 + bq*8;
        *(s16x8*)&Bh[bn][bq*8] = *(const s16x8*)&W1h[bb];
        *(s16x8*)&Bl[bn][bq*8] = *(const s16x8*)&W1l[bb];
      }
      __syncthreads();
      int cofs = (lane >> 4)*8;
      int ar = wm*16 + (lane & 15);
      s16x8 ahf = *(const s16x8*)&Ah[ar][cofs];
      s16x8 alf = *(const s16x8*)&Al[ar][cofs];
#pragma unroll
      for (int fn = 0; fn < 2; fn++) {
        int br = wn*32 + fn*16 + (lane & 15);
        s16x8 bhf = *(const s16x8*)&Bh[br][cofs];
        s16x8 blf = *(const s16x8*)&Bl[br][cofs];
        acc[fn] = __builtin_amdgcn_mfma_f32_16x16x32_bf16(ahf, bhf, acc[fn], 0, 0, 0);
        acc[fn] = __builtin_amdgcn_mfma_f32_16x16x32_bf16(alf, bhf, acc[fn], 0, 0, 0);
        acc[fn] = __builtin_amdgcn_mfma_f32_16x16x32_bf16(ahf, blf, acc[fn], 0, 0, 0);
      }
      __syncthreads();
    }
#pragma unroll
    for (int jj = 0; jj < 4; jj++) {
      int row = wm*16 + (lane >> 4)*4 + jj;
#pragma unroll
      for (int fn = 0; fn < 2; fn++) {
        int col = n0 + wn*32 + fn*16 + (lane & 15);
        hid[row][col] = split_pk(gelu_tanh(acc[fn][jj]));
      }
    }
  }
  __syncthreads();

  // ================= layer 2: out = hid @ w2; Y[src] += gain*out (atomic) =================
  for (int n0 = 0; n0 < 512; n0 += 64) {
    f32x4 acc[2];
    acc[0] = (f32x4){0.f,0.f,0.f,0.f};
    acc[1] = (f32x4){0.f,0.f,0.f,0.f};
    for (int k0 = 0; k0 < 512; k0 += 32) {
      {
        size_t bb = wofs + (size_t)(n0 + bn)*DM + k0 + bq*8;
        *(s16x8*)&Bh[bn][bq*8] = *(const s16x8*)&W2h[bb];
        *(s16x8*)&Bl[bn][bq*8] = *(const s16x8*)&W2l[bb];
      }
      __syncthreads();
      int cofs = (lane >> 4)*8;
      int ar = wm*16 + (lane & 15);
      u32x4 pa  = *(const u32x4*)&hid[ar][k0 + cofs];
      u32x4 pb2 = *(const u32x4*)&hid[ar][k0 + cofs + 4];
      s16x8 hv, lv;
#pragma unroll
      for (int q = 0; q < 4; q++) {
        hv[q]   = (short)(pa[q] & 0xffffu);  lv[q]   = (short)(pa[q] >> 16);
        hv[q+4] = (short)(pb2[q] & 0xffffu); lv[q+4] = (short)(pb2[q] >> 16);
      }
#pragma unroll
      for (int fn = 0; fn < 2; fn++) {
        int br = wn*32 + fn*16 + (lane & 15);
        s16x8 bhf = *(const s16x8*)&Bh[br][cofs];
        s16x8 blf = *(const s16x8*)&Bl[br][cofs];
        acc[fn] = __builtin_amdgcn_mfma_f32_16x16x32_bf16(hv, bhf, acc[fn], 0, 0, 0);
        acc[fn] = __builtin_amdgcn_mfma_f32_16x16x32_bf16(lv, bhf, acc[fn], 0, 0, 0);
        acc[fn] = __builtin_amdgcn_mfma_f32_16x16x32_bf16(hv, blf, acc[fn], 0, 0, 0);
      }
      __syncthreads();
    }
#pragma unroll
    for (int jj = 0; jj < 4; jj++) {
      int row = wm*16 + (lane >> 4)*4 + jj;
      int src = srcs[row];
      float g = gains[row];
      if (src >= 0) {
#pragma unroll
        for (int fn = 0; fn < 2; fn++) {
          int col = n0 + wn*32 + fn*16 + (lane & 15);
          atomicAdd(&Y[(size_t)src*DM + col], g * acc[fn][jj]);
        }
      }
    }
  }
}

// ---------------- classifier epilogue ----------------
__global__ __launch_bounds__(256) void k_h1norm(
    float* __restrict__ H, const float* __restrict__ bias, const float* __restrict__ w) {
  int r = blockIdx.x, t = threadIdx.x;
  size_t base = (size_t)r*1000;
  float v[4]; float ss = 0.f;
#pragma unroll
  for (int i = 0; i < 4; i++) {
    int c = t + i*256;
    float x = 0.f;
    if (c < 1000) { x = fmaxf(H[base+c] + bias[c], 0.f); }
    v[i] = x; ss += x*x;
  }
#pragma unroll
  for (int o = 32; o; o >>= 1) ss += __shfl_xor(ss, o);
  __shared__ float red[4];
  if ((t & 63) == 0) red[t>>6] = ss;
  __syncthreads();
  float tot = red[0]+red[1]+red[2]+red[3];
  float sc = rsqrtf(tot * 0.001f + 1e-6f);
#pragma unroll
  for (int i = 0; i < 4; i++) {
    int c = t + i*256;
    if (c < 1000) H[base+c] = v[i]*sc*w[c];
  }
}

__global__ __launch_bounds__(128) void k_h2(
    const float* __restrict__ H1, const float* __restrict__ W2c,
    const float* __restrict__ b2, const float* __restrict__ rms2,
    float* __restrict__ H2) {
  __shared__ float hrow[1000];
  __shared__ float sq[128];
  int r = blockIdx.x, t = threadIdx.x;
  for (int c = t; c < 1000; c += 128) hrow[c] = H1[(size_t)r*1000+c];
  __syncthreads();
  float acc = 0.f;
  if (t < 100) {
    for (int k = 0; k < 1000; k++) acc += hrow[k]*W2c[k*100+t];
    acc = fmaxf(acc + b2[t], 0.f);
  }
  sq[t] = (t < 100) ? acc*acc : 0.f;
  __syncthreads();
  if (t < 64) sq[t] += sq[t+64];
  __syncthreads();
  if (t == 0) { float s = 0.f; for (int i = 0; i < 64; i++) s += sq[i]; sq[0] = s; }
  __syncthreads();
  float sc = rsqrtf(sq[0]*0.01f + 1e-6f);
  if (t < 100) H2[(size_t)r*100+t] = acc*sc*rms2[t];
}

__global__ __launch_bounds__(256) void k_out(
    const float* __restrict__ H2, const float* __restrict__ w3,
    const float* __restrict__ b3, float* __restrict__ out) {
  int b = blockIdx.x*256 + threadIdx.x;
  if (b >= NB) return;
  float acc = b3[0];
  for (int k = 0; k < 100; k++) acc += H2[(size_t)b*100+k]*w3[k];
  out[b] = acc;
}

extern "C" void kernel_launch(void* const* d_in, const int* in_sizes, int n_in,
                              void* d_out, int out_size, void* d_ws, size_t ws_size,
                              hipStream_t stream) {
  const int*   ta   = (const int*)d_in[0];
  const int*   tb   = (const int*)d_in[1];
  const int*   tp   = (const int*)d_in[2];
  const float* Wa   = (const float*)d_in[3];
  const float* Wb   = (const float*)d_in[4];
  const float* Wp   = (const float*)d_in[5];
  const float* AW   = (const float*)d_in[6];
  const float* rmsd = (const float*)d_in[7];
  const float* Wg   = (const float*)d_in[8];
  const float* W1   = (const float*)d_in[9];
  const float* W2   = (const float*)d_in[10];
  const float* cw1  = (const float*)d_in[11];
  const float* cb1  = (const float*)d_in[12];
  const float* rms1 = (const float*)d_in[13];
  const float* cw2  = (const float*)d_in[14];
  const float* cb2  = (const float*)d_in[15];
  const float* rms2 = (const float*)d_in[16];
  const float* cw3  = (const float*)d_in[17];
  const float* cb3  = (const float*)d_in[18];
  float* out = (float*)d_out;

  const size_t WMAT = (size_t)DM*DM;        // 262,144

  char* ws = (char*)d_ws;
  float*   X   = (float*)ws;                               // 159.4 MB f32 residual (exact)
  ushortt* Xh  = (ushortt*)(ws + 159383552ULL);            // 79.7 MB
  ushortt* Xl  = (ushortt*)(ws + 239075328ULL);            // 79.7 MB
  float*   Q0  = (float*)(ws + 318767104ULL);              // 119.5 MB QKV chunk scratch
  // Aliases inside Q0 (used only after encoders are done):
  ushortt* W1h = (ushortt*)(ws + 318767104ULL);            // k-major planes, 8.39 MB each
  ushortt* W1l = W1h + 16*WMAT;
  ushortt* W2h = W1l + 16*WMAT;
  ushortt* W2l = W2h + 16*WMAT;                            // ends +33.55 MB
  float*   P   = (float*)(ws + 318767104ULL + 33554432ULL);// classifier partials 32.8 MB
  // cw1 k-major planes alias the (dead-after-final-split) X region:
  ushortt* CW1h = (ushortt*)ws;                            // 77.8 MB
  ushortt* CW1l = CW1h + (size_t)38912*1000;               // ends 155.6 MB < 159.4 ✓
  ushortt* AWh = (ushortt*)(ws + 438304768ULL);            // k-major planes
  ushortt* AWl = AWh + 16*WMAT;                            // ends 455,081,984
  int*     rec_src  = (int*)(ws + 455081984ULL);
  float*   rec_gain = (float*)(ws + 457572352ULL);
  int*     cnt      = (int*)(ws + 460062720ULL);
  float*   h1       = (float*)(ws + 460062976ULL);
  float*   h2       = (float*)(ws + 464158976ULL);         // ends ~464.6 MB

  // 0. relayout attention weights -> k-major hi/lo planes
  k_relayout<<<dim3(8,8,16), 256, 0, stream>>>(AW, AWh, AWl, 512, 512);

  // 1. embedding + PE -> X (f32) + planes
  k_embed<<<dim3((int)((NELM+255)/256)), 256, 0, stream>>>(ta,tb,tp,Wa,Wb,Wp,X,Xh,Xl);

  // 2-4. per-branch encoders, 2 batch-chunks of 512
  const int segs[3]  = {SSA, SSB, SSP};
  const int boffs[3] = {0, SSA, SSA+SSB};
  for (int br = 0; br < 3; br++) {
    int seg = segs[br], boff = boffs[br];
    const int CHB = 512;
    int M = CHB*seg;
    long long qst = (long long)M*DM;
    float* Qr = Q0; float* Kr = Q0 + qst; float* Vr = Q0 + 2*qst;
    for (int ch = 0; ch < NB/CHB; ch++) {
      int cb0 = ch*CHB;
      k_mfma<0,1,1><<<dim3(M/128,12,1),256,0,stream>>>(
          Xh, Xl, AWh + (size_t)br*4*WMAT, AWl + (size_t)br*4*WMAT, Q0,
          1536,512, 512,512,0,  seg,NS,boff,seg,cb0, (long long)WMAT,9, qst, 0);
      k_attn2<<<dim3(CHB,NH),256,0,stream>>>(Qr, Kr, Vr, seg);
      k_mfma<1,0,1><<<dim3(M/128,4,1),256,0,stream>>>(
          (const ushortt*)Qr, (const ushortt*)Qr + (size_t)seg*64,
          AWh + (size_t)(br*4+3)*WMAT, AWl + (size_t)(br*4+3)*WMAT, Vr,
          512,512, 0,512,512,  seg,seg,0,seg,0, 0,30, 0, 0);
      k_addnorm<<<M,256,0,stream>>>(X, Xh, Xl, Vr, rmsd, seg, boff, cb0);
    }
  }

  // 5. full-sequence encoder, 4 batch-chunks of 256
  {
    const int CH = 256;
    int M = CH*NS;                       // 19456
    long long qst = (long long)M*DM;
    float* Qr = Q0; float* Kr = Q0 + qst; float* Vr = Q0 + 2*qst;
    for (int ch = 0; ch < NB/CH; ch++) {
      int cb0 = ch*CH;
      k_mfma<0,1,1><<<dim3(M/128,12,1),256,0,stream>>>(
          Xh, Xl, AWh + (size_t)12*WMAT, AWl + (size_t)12*WMAT, Q0,
          1536,512, 512,512,0,  NS,NS,0,NS,cb0, (long long)WMAT,9, qst, 0);
      k_attn2<<<dim3(CH,NH),256,0,stream>>>(Qr, Kr, Vr, NS);
      k_mfma<1,0,1><<<dim3(M/128,4,1),256,0,stream>>>(
          (const ushortt*)Qr, (const ushortt*)Qr + (size_t)NS*64,
          AWh + (size_t)15*WMAT, AWl + (size_t)15*WMAT, Vr,
          512,512, 0,512,512,  NS,NS,0,NS,0, 0,30, 0, 0);
      k_addnorm<<<M,256,0,stream>>>(X, Xh, Xl, Vr, rmsd, NS, 0, cb0);
    }
  }

  // 6. MoE: expert weights -> k-major planes in dead Q0; route on f32 X; both ranks in one launch
  k_relayout<<<dim3(8,8,16), 256, 0, stream>>>(W1, W1h, W1l, 512, 512);
  k_relayout<<<dim3(8,8,16), 256, 0, stream>>>(W2, W2h, W2l, 512, 512);
  hipError_t e1 = hipMemsetAsync(cnt, 0, NE*2*sizeof(int), stream); (void)e1;
  k_route<<<NB,256,0,stream>>>(X, Wg, rec_src, rec_gain, cnt);
  k_expert_mfma<<<dim3((NSLOT+31)/32, NE, 2),256,0,stream>>>(Xh, Xl, W1h, W1l, W2h, W2l, X, rec_src, rec_gain, cnt);

  // 7. classifier: split post-MoE X -> planes (X now dead), cw1 -> k-major planes in X region,
  //    split-K GEMM (MW=4 register cap), reduce, epilogue
  k_split_planes<<<dim3((int)((NELM+255)/256)), 256, 0, stream>>>(X, Xh, Xl, (int)NELM);
  k_relayout<<<dim3(608,16,1), 256, 0, stream>>>(cw1, CW1h, CW1l, 38912, 1000);
  k_mfma<0,0,4><<<dim3(NB/128,(1000+127)/128,KSPLIT),256,0,stream>>>(
      Xh, Xl, CW1h, CW1l, P,
      1000, (NS*DM)/KSPLIT, NS*DM, NS*DM, 1000,  NB,0,0,1,0, 0,30, 0, (long long)NB*1000);
  k_ksum<<<dim3((NB*1000+255)/256),256,0,stream>>>(P, h1);
  k_h1norm<<<NB,256,0,stream>>>(h1, cb1, rms1);
  k_h2<<<NB,128,0,stream>>>(h1, cw2, cb2, rms2, h2);
  k_out<<<dim3((NB+255)/256),256,0,stream>>>(h2, cw3, cb3, out);
}